// Round 8
// baseline (60.142 us; speedup 1.0000x reference)
//
#include <hip/hip_runtime.h>
#include <math.h>

#define NHEADS 4
#define HDIM   32
#define DMODEL 128
#define SLEN   8192
#define BATCH  8
#define QKVC   384   // 3 * NHEADS * HDIM

typedef __bf16 bf16x8 __attribute__((ext_vector_type(8)));
typedef float  f32x4  __attribute__((ext_vector_type(4)));

// round-to-nearest-even f32 -> bf16 bits
static __device__ __forceinline__ unsigned short f2bf(float f) {
    union { float f; unsigned int u; } v; v.f = f;
    unsigned int r = (v.u + 0x7FFFu + ((v.u >> 16) & 1u)) >> 16;
    return (unsigned short)r;
}
// hardware cvt pack (v_cvt_pk_bf16_f32)
static __device__ __forceinline__ unsigned int pk2(float a, float b) {
    unsigned short ua = __builtin_bit_cast(unsigned short, (__bf16)a);
    unsigned short ub = __builtin_bit_cast(unsigned short, (__bf16)b);
    return (unsigned int)ua | ((unsigned int)ub << 16);
}
static __device__ __forceinline__ float bf_lo(unsigned int u) {
    union { unsigned int u; float f; } v; v.u = u << 16; return v.f;
}
static __device__ __forceinline__ float bf_hi(unsigned int u) {
    union { unsigned int u; float f; } v; v.u = u & 0xffff0000u; return v.f;
}

// ---------------------------------------------------------------------------
// Kernel P: prep. blockIdx segments:
//   [0,64) : W_out f32[8192][128] -> Wt bf16 [128][8192] (transpose+cvt)
//   [64,88): W_qkv -> MFMA A-fragment buffer wfb (bf16, fragment order)
// ---------------------------------------------------------------------------
__global__ __launch_bounds__(256) void k_prep(
    const float* __restrict__ Wout, unsigned short* __restrict__ Wt,
    const float* __restrict__ Wqkv, unsigned short* __restrict__ wfb)
{
    const int tid = threadIdx.x;
    const int bx  = blockIdx.x;

    if (bx < 64) {
        __shared__ unsigned short ts[128][136];
        const float* src = Wout + (long)bx * 128 * 128;
        #pragma unroll
        for (int i = 0; i < 64; ++i) {
            const int idx = tid + i * 256;
            const int kk = idx >> 7, n = idx & 127;
            ts[n][kk] = f2bf(src[idx]);
        }
        __syncthreads();
        #pragma unroll
        for (int i = 0; i < 64; ++i) {
            const int idx = tid + i * 256;
            const int n = idx >> 7, kk = idx & 127;
            Wt[(long)n * SLEN + bx * 128 + kk] = ts[n][kk];
        }
    } else {
        const int idx  = (bx - 64) * 256 + tid;   // 0..6143
        const int lane = idx & 63;
        const int ks   = (idx >> 6) & 3;
        const int rest = idx >> 8;                // 0..23
        const int j    = rest % 6;
        const int w    = rest / 6;
        const int ch   = w * 96 + j * 16 + (lane & 15);
        const int kb   = ks * 32 + (lane >> 4) * 8;
        unsigned short t[8];
        #pragma unroll
        for (int e = 0; e < 8; ++e) t[e] = f2bf(Wqkv[(kb + e) * QKVC + ch]);
        *(uint4*)(wfb + (long)idx * 8) = *(const uint4*)t;
    }
}

// ---------------------------------------------------------------------------
// Kernel 1: QKV projection GEMM only (bf16 MFMA).
// 2048 blocks x 256 thr; one 32-position tile per block; ONE barrier.
// Output: qkvT tiled [tile][pos 32][ch 384] bf16 (+bias), written straight
// from accumulators as b64 stores (lane owns 4 consecutive channels).
// No softmax, no qsm, no second barrier -> low VGPR, streaming.
// ---------------------------------------------------------------------------
__global__ __launch_bounds__(256, 3) void k_qkv(
    const float* __restrict__ x,
    const unsigned short* __restrict__ wfb,
    const float* __restrict__ bqkv,
    unsigned short* __restrict__ qkvT)       // [2048][32][384] bf16
{
    __shared__ unsigned short xs[32 * 136];  // x tile bf16

    const int tid  = threadIdx.x;
    const int lane = tid & 63;
    const int wave = tid >> 6;
    const int l16  = lane & 15;
    const int lhi  = lane >> 4;
    const long p0  = (long)blockIdx.x * 32;

    // stage x tile: 16 f32 per thread, hw cvt to bf16, coalesced
    {
        const int spos = tid >> 3, sseg = tid & 7;
        const float* src = x + (p0 + spos) * DMODEL + sseg * 16;
        float4 a0 = *(const float4*)(src);
        float4 a1 = *(const float4*)(src + 4);
        float4 a2 = *(const float4*)(src + 8);
        float4 a3 = *(const float4*)(src + 12);
        unsigned int t[8] = {
            pk2(a0.x, a0.y), pk2(a0.z, a0.w), pk2(a1.x, a1.y), pk2(a1.z, a1.w),
            pk2(a2.x, a2.y), pk2(a2.z, a2.w), pk2(a3.x, a3.y), pk2(a3.z, a3.w) };
        *(uint4*)(xs + spos * 136 + sseg * 16)     = ((const uint4*)t)[0];
        *(uint4*)(xs + spos * 136 + sseg * 16 + 8) = ((const uint4*)t)[1];
    }
    __syncthreads();

    // MFMA: qkv^T (rows = channels, cols = positions)
    f32x4 acc[6][2];
    #pragma unroll
    for (int j = 0; j < 6; ++j)
        #pragma unroll
        for (int nt = 0; nt < 2; ++nt) acc[j][nt] = (f32x4){0.f, 0.f, 0.f, 0.f};

    const unsigned short* wbase = wfb + ((long)(wave * 24) * 64 + lane) * 8;
    #pragma unroll
    for (int ks = 0; ks < 4; ++ks) {
        const bf16x8 xf0 = __builtin_bit_cast(bf16x8,
            *(const uint4*)(xs + l16 * 136 + ks * 32 + lhi * 8));
        const bf16x8 xf1 = __builtin_bit_cast(bf16x8,
            *(const uint4*)(xs + (16 + l16) * 136 + ks * 32 + lhi * 8));
        #pragma unroll
        for (int j = 0; j < 6; ++j) {
            const bf16x8 wj = __builtin_bit_cast(bf16x8,
                *(const uint4*)(wbase + (j * 4 + ks) * 512));
            acc[j][0] = __builtin_amdgcn_mfma_f32_16x16x32_bf16(wj, xf0, acc[j][0], 0, 0, 0);
            acc[j][1] = __builtin_amdgcn_mfma_f32_16x16x32_bf16(wj, xf1, acc[j][1], 0, 0, 0);
        }
    }

    // acc (+bias) -> global qkvT[tile][pos][ch], b64 per (j,nt)
    unsigned short* tbase = qkvT + (long)blockIdx.x * 32 * QKVC;
    #pragma unroll
    for (int j = 0; j < 6; ++j) {
        const float4 bb = *(const float4*)(bqkv + wave * 96 + j * 16 + lhi * 4);
        const int ch = wave * 96 + j * 16 + lhi * 4;
        #pragma unroll
        for (int nt = 0; nt < 2; ++nt) {
            const int p = nt * 16 + l16;
            uint2 u;
            u.x = pk2(acc[j][nt][0] + bb.x, acc[j][nt][1] + bb.y);
            u.y = pk2(acc[j][nt][2] + bb.z, acc[j][nt][3] + bb.w);
            *(uint2*)(tbase + p * QKVC + ch) = u;
        }
    }
}

// ---------------------------------------------------------------------------
// Kernel 2: per-position head-mixing attention. Zero LDS, zero barriers.
// 2048 blocks x 256 thr; thread = (p = tid>>3, qh = (tid>>1)&3, h = tid&1).
// Reads qkvT tile (24 KB, L1-resident), 16-d score partial + shfl_xor(1),
// softmax over 4 heads, 16-channel PV, coalesced bf16 store.
// ---------------------------------------------------------------------------
__global__ __launch_bounds__(256) void k_attn(
    const unsigned short* __restrict__ qkvT,
    unsigned short* __restrict__ attn_out)   // bf16 [65536][128]
{
    const int tid = threadIdx.x;
    const int p   = tid >> 3;
    const int qh  = (tid >> 1) & 3;
    const int h   = tid & 1;
    const unsigned short* row = qkvT + ((long)blockIdx.x * 32 + p) * QKVC;
    const float scale = 0.17677669529663687f;   // 32^-0.5

    // q half: 16 f32
    float qf[16];
    {
        const unsigned short* qp = row + qh * 96 + h * 16;
        const uint4 q0 = *(const uint4*)(qp);
        const uint4 q1 = *(const uint4*)(qp + 8);
        const unsigned int* w0 = (const unsigned int*)&q0;
        const unsigned int* w1 = (const unsigned int*)&q1;
        #pragma unroll
        for (int k = 0; k < 4; ++k) {
            qf[2 * k]     = bf_lo(w0[k]);  qf[2 * k + 1] = bf_hi(w0[k]);
            qf[8 + 2 * k] = bf_lo(w1[k]);  qf[9 + 2 * k] = bf_hi(w1[k]);
        }
    }
    // scores
    float sc[NHEADS];
    #pragma unroll
    for (int kh = 0; kh < NHEADS; ++kh) {
        const unsigned short* kp = row + kh * 96 + 32 + h * 16;
        const uint4 k0 = *(const uint4*)(kp);
        const uint4 k1 = *(const uint4*)(kp + 8);
        const unsigned int* w0 = (const unsigned int*)&k0;
        const unsigned int* w1 = (const unsigned int*)&k1;
        float s = 0.f;
        #pragma unroll
        for (int k = 0; k < 4; ++k) {
            s = fmaf(bf_lo(w0[k]), qf[2 * k], s);
            s = fmaf(bf_hi(w0[k]), qf[2 * k + 1], s);
            s = fmaf(bf_lo(w1[k]), qf[8 + 2 * k], s);
            s = fmaf(bf_hi(w1[k]), qf[9 + 2 * k], s);
        }
        sc[kh] = (s + __shfl_xor(s, 1)) * scale;
    }
    const float m = fmaxf(fmaxf(sc[0], sc[1]), fmaxf(sc[2], sc[3]));
    float ew[NHEADS], sum = 0.f;
    #pragma unroll
    for (int kh = 0; kh < NHEADS; ++kh) { ew[kh] = __expf(sc[kh] - m); sum += ew[kh]; }
    const float inv = 1.f / sum;
    #pragma unroll
    for (int kh = 0; kh < NHEADS; ++kh) ew[kh] *= inv;

    // PV: 16 output channels d = h*16..h*16+15
    float o[16];
    #pragma unroll
    for (int e = 0; e < 16; ++e) o[e] = 0.f;
    #pragma unroll
    for (int kh = 0; kh < NHEADS; ++kh) {
        const float wk = ew[kh];
        const unsigned short* vp = row + kh * 96 + 64 + h * 16;
        const uint4 v0 = *(const uint4*)(vp);
        const uint4 v1 = *(const uint4*)(vp + 8);
        const unsigned int* w0 = (const unsigned int*)&v0;
        const unsigned int* w1 = (const unsigned int*)&v1;
        #pragma unroll
        for (int k = 0; k < 4; ++k) {
            o[2 * k]     = fmaf(wk, bf_lo(w0[k]), o[2 * k]);
            o[2 * k + 1] = fmaf(wk, bf_hi(w0[k]), o[2 * k + 1]);
            o[8 + 2 * k] = fmaf(wk, bf_lo(w1[k]), o[8 + 2 * k]);
            o[9 + 2 * k] = fmaf(wk, bf_hi(w1[k]), o[9 + 2 * k]);
        }
    }
    unsigned int ow[8];
    #pragma unroll
    for (int e = 0; e < 8; ++e) ow[e] = pk2(o[2 * e], o[2 * e + 1]);
    unsigned short* dst = attn_out + ((long)blockIdx.x * 32 + p) * DMODEL + qh * 32 + h * 16;
    *(uint4*)(dst)     = ((const uint4*)ow)[0];
    *(uint4*)(dst + 8) = ((const uint4*)ow)[1];
}

// ---------------------------------------------------------------------------
// Kernel 3: final GEMM partials via bf16 MFMA (R6-proven).
//   C(1024x128) = Aflat(1024x8192 bf16) @ W(8192x128)
// ---------------------------------------------------------------------------
__global__ __launch_bounds__(256, 2) void k_fgemm_mfma(
    const unsigned short* __restrict__ attnBf,   // [1024][8192] bf16 (flat view)
    const unsigned short* __restrict__ WtBf,     // [128][8192] bf16
    float* __restrict__ P)                       // [16][1024][128] f32 partials
{
    __shared__ unsigned short As[64][136];
    __shared__ unsigned short Ws[128][136];

    const int tid   = threadIdx.x;
    const int mtile = blockIdx.x >> 4;
    const int kc    = blockIdx.x & 15;
    const int lane  = tid & 63;
    const int wave  = tid >> 6;
    const int l16   = lane & 15;
    const int lhi   = lane >> 4;

    f32x4 acc[4][2];
    #pragma unroll
    for (int mf = 0; mf < 4; ++mf)
        #pragma unroll
        for (int nt = 0; nt < 2; ++nt) acc[mf][nt] = (f32x4){0.f, 0.f, 0.f, 0.f};

    for (int st = 0; st < 4; ++st) {
        const int k0 = kc * 512 + st * 128;
        __syncthreads();
        #pragma unroll
        for (int i = 0; i < 4; ++i) {
            const int c = tid + i * 256;
            const int m = c >> 4, k8 = c & 15;
            const uint4 v = *(const uint4*)(attnBf + (long)(mtile * 64 + m) * SLEN + k0 + k8 * 8);
            *(uint4*)(&As[m][k8 * 8]) = v;
        }
        #pragma unroll
        for (int i = 0; i < 8; ++i) {
            const int c = tid + i * 256;
            const int n = c >> 4, k8 = c & 15;
            const uint4 v = *(const uint4*)(WtBf + (long)n * SLEN + k0 + k8 * 8);
            *(uint4*)(&Ws[n][k8 * 8]) = v;
        }
        __syncthreads();

        #pragma unroll
        for (int ks = 0; ks < 4; ++ks) {
            const int kk = ks * 32 + lhi * 8;
            bf16x8 af[4], bfr[2];
            #pragma unroll
            for (int mf = 0; mf < 4; ++mf)
                af[mf] = __builtin_bit_cast(bf16x8, *(const uint4*)(&As[mf * 16 + l16][kk]));
            #pragma unroll
            for (int nt = 0; nt < 2; ++nt)
                bfr[nt] = __builtin_bit_cast(bf16x8, *(const uint4*)(&Ws[(wave * 2 + nt) * 16 + l16][kk]));
            #pragma unroll
            for (int mf = 0; mf < 4; ++mf)
                #pragma unroll
                for (int nt = 0; nt < 2; ++nt)
                    acc[mf][nt] = __builtin_amdgcn_mfma_f32_16x16x32_bf16(af[mf], bfr[nt], acc[mf][nt], 0, 0, 0);
        }
    }

    float* Pp = P + ((long)kc * 1024 + mtile * 64) * 128;
    #pragma unroll
    for (int mf = 0; mf < 4; ++mf) {
        #pragma unroll
        for (int nt = 0; nt < 2; ++nt) {
            const int n = (wave * 2 + nt) * 16 + l16;
            #pragma unroll
            for (int r = 0; r < 4; ++r) {
                const int m = mf * 16 + lhi * 4 + r;
                Pp[m * 128 + n] = acc[mf][nt][r];
            }
        }
    }
}

// ---------------------------------------------------------------------------
// Kernel 4: reduce 16 K-chunk partials + bias -> out (also clears poison).
// ---------------------------------------------------------------------------
__global__ __launch_bounds__(256) void k_reduce(
    const float* __restrict__ P, const float* __restrict__ bout,
    float* __restrict__ out)
{
    const int idx = blockIdx.x * 256 + threadIdx.x;
    float v = bout[idx & 127];
    #pragma unroll
    for (int kcc = 0; kcc < 16; ++kcc) v += P[(long)kcc * 131072 + idx];
    out[idx] = v;
}

// ---------------------------------------------------------------------------
extern "C" void kernel_launch(void* const* d_in, const int* in_sizes, int n_in,
                              void* d_out, int out_size, void* d_ws, size_t ws_size,
                              hipStream_t stream)
{
    const float* x    = (const float*)d_in[0];
    const float* Wqkv = (const float*)d_in[1];
    const float* bqkv = (const float*)d_in[2];
    const float* Wout = (const float*)d_in[3];
    const float* bout = (const float*)d_in[4];
    float* out = (float*)d_out;

    // ws: [0,16M) attn bf16 | [16,18M) Wt bf16 | [18,26M) P f32
    //     [26,27M) wfb bf16 | [27,75M) qkvT bf16
    unsigned short* attnBf = (unsigned short*)d_ws;
    unsigned short* WtBf   = (unsigned short*)((char*)d_ws + (16u << 20));
    float*          P      = (float*)((char*)d_ws + (18u << 20));
    unsigned short* wfb    = (unsigned short*)((char*)d_ws + (26u << 20));
    unsigned short* qkvT   = (unsigned short*)((char*)d_ws + (27u << 20));

    k_prep<<<88, 256, 0, stream>>>(Wout, WtBf, Wqkv, wfb);
    k_qkv<<<2048, 256, 0, stream>>>(x, wfb, bqkv, qkvT);
    k_attn<<<2048, 256, 0, stream>>>(qkvT, attnBf);
    k_fgemm_mfma<<<256, 256, 0, stream>>>(attnBf, WtBf, P);
    k_reduce<<<512, 256, 0, stream>>>(P, bout, out);
}